// Round 6
// baseline (815.541 us; speedup 1.0000x reference)
//
#include <hip/hip_runtime.h>
#include <hip/hip_bf16.h>

#define BSZ 2
#define LLEN 2048
#define NHEADS 32
#define HEADDIM 64
#define DSTATE 128
#define DCONV 4
#define DINNER (NHEADS * HEADDIM)                  // 2048
#define DPROJ  (2 * DINNER + 2 * DSTATE + NHEADS)  // 4384
#define Q 128                                      // scan chunk length
#define NCHUNK (LLEN / Q)                          // 16

__device__ __forceinline__ float sigm(float x) { return 1.0f / (1.0f + __expf(-x)); }

// Robust python-int scalar read (int32 bits or float32 bits).
__device__ __forceinline__ float int_scalar(const int* p) {
    int i = *p;
    if (i >= 0 && i <= 1000000) return (float)i;
    return __int_as_float(i);
}

// ---------------------------------------------------------------------------
// Kernel 1: B/C conv channels + (dt, dA) into fp32 workspace. (round-5 proven)
// ---------------------------------------------------------------------------
__global__ __launch_bounds__(256) void pre_kernel(
    const float* __restrict__ zx, const float* __restrict__ cw,
    const float* __restrict__ cb, const float* __restrict__ dtb,
    const float* __restrict__ alog, const float* __restrict__ dts,
    const int* __restrict__ mn_p, const int* __restrict__ mx_p,
    float* __restrict__ Bc, float* __restrict__ Cc,
    float2* __restrict__ dtA)
{
    const int bl  = blockIdx.x;            // 0 .. B*L-1
    const int b   = bl / LLEN;
    const int l   = bl % LLEN;
    const int tid = threadIdx.x;           // 0..255 == 2*DSTATE channels

    {
        const int c = DINNER + tid;        // conv channel (B/C region)
        float acc = cb[c];
        #pragma unroll
        for (int k = 0; k < DCONV; k++) {
            int lk = l - (DCONV - 1) + k;
            if (lk >= 0) {
                acc += cw[(size_t)c * DCONV + k] *
                       zx[((size_t)b * LLEN + lk) * DPROJ + DINNER + c];
            }
        }
        float v = acc * sigm(acc);
        if (tid < DSTATE) Bc[(size_t)bl * DSTATE + tid] = v;
        else              Cc[(size_t)bl * DSTATE + (tid - DSTATE)] = v;
    }

    if (tid < NHEADS) {
        float raw = zx[(size_t)bl * DPROJ + (DPROJ - NHEADS) + tid];
        float v   = raw * dts[tid] + dtb[tid];
        float sp  = (v > 20.0f) ? v : log1pf(__expf(v));
        float dt  = fminf(fmaxf(sp, int_scalar(mn_p)), int_scalar(mx_p));
        float A   = -__expf(alog[tid]);
        dtA[(size_t)bl * NHEADS + tid] = make_float2(dt, __expf(dt * A));
    }
}

// ---------------------------------------------------------------------------
// Phase A: per-chunk local end-state (zero init) + total decay.
// Grid (NCHUNK, NHEADS/4, BSZ) x 256. Wave = one head; lane = p (all 64).
// Each lane holds all 128 states in VGPRs. B is wave-uniform (broadcast).
// SA layout per (b,h,c): [n][p]  (coalesced stores/loads over lanes).
// ---------------------------------------------------------------------------
__global__ __launch_bounds__(256, 1) void state_kernel(
    const float* __restrict__ zx, const float* __restrict__ cw,
    const float* __restrict__ cb,
    const float* __restrict__ Bc, const float2* __restrict__ dtA,
    float* __restrict__ SA, float* __restrict__ dtot)
{
    const int c    = blockIdx.x;                        // chunk
    const int h    = blockIdx.y * 4 + (threadIdx.x >> 6);
    const int b    = blockIdx.z;
    const int lane = threadIdx.x & 63;
    const int p    = lane;
    const int t0   = c * Q;
    const int cx   = h * HEADDIM + p;

    const float w0 = cw[(size_t)cx * DCONV + 0];
    const float w1 = cw[(size_t)cx * DCONV + 1];
    const float w2 = cw[(size_t)cx * DCONV + 2];
    const float w3 = cw[(size_t)cx * DCONV + 3];
    const float bx = cb[cx];

    const float*  px  = zx + ((size_t)b * LLEN + t0) * DPROJ + DINNER + cx;
    const float4* pB4 = (const float4*)(Bc + ((size_t)b * LLEN + t0) * DSTATE);
    const float2* pd  = dtA + ((size_t)b * LLEN + t0) * NHEADS + h;

    float xh0 = 0.f, xh1 = 0.f, xh2 = 0.f;              // conv history
    if (c > 0) { xh0 = px[-3 * DPROJ]; xh1 = px[-2 * DPROJ]; xh2 = px[-1 * DPROJ]; }

    float st[DSTATE];
    #pragma unroll
    for (int n = 0; n < DSTATE; n++) st[n] = 0.f;
    float aprod = 1.f;

    // depth-2 ring for per-lane x and uniform (dt,dA)
    float  xr[2]; float2 dr[2];
    xr[0] = px[0];  xr[1] = px[DPROJ];
    dr[0] = pd[0];  dr[1] = pd[NHEADS];

    for (int t = 0; t < Q; t++) {
        const float  xraw = xr[t & 1];
        const float2 da   = dr[t & 1];
        int tn = t + 2; if (tn > Q - 1) tn = Q - 1;
        xr[t & 1] = px[(size_t)tn * DPROJ];
        dr[t & 1] = pd[(size_t)tn * NHEADS];

        const float cv   = bx + w0 * xh0 + w1 * xh1 + w2 * xh2 + w3 * xraw;
        const float xs   = cv * sigm(cv);
        const float coef = da.x * xs;
        const float dAv  = da.y;
        aprod *= dAv;
        xh0 = xh1; xh1 = xh2; xh2 = xraw;

        const float4* row = pB4 + (size_t)t * (DSTATE / 4);
        #pragma unroll
        for (int half = 0; half < 2; half++) {
            float4 Bt[16];
            #pragma unroll
            for (int i = 0; i < 16; i++) Bt[i] = row[half * 16 + i];
            #pragma unroll
            for (int i = 0; i < 16; i++) {
                const int n = half * 64 + i * 4;
                st[n + 0] = dAv * st[n + 0] + coef * Bt[i].x;
                st[n + 1] = dAv * st[n + 1] + coef * Bt[i].y;
                st[n + 2] = dAv * st[n + 2] + coef * Bt[i].z;
                st[n + 3] = dAv * st[n + 3] + coef * Bt[i].w;
            }
        }
    }

    float* sa = SA + (((size_t)(b * NHEADS + h)) * NCHUNK + c) * (HEADDIM * DSTATE);
    #pragma unroll
    for (int n = 0; n < DSTATE; n++) sa[(size_t)n * HEADDIM + p] = st[n];
    if (lane == 0) dtot[((size_t)(b * NHEADS + h)) * NCHUNK + c] = aprod;
}

// ---------------------------------------------------------------------------
// Phase B: sequential chunk combine per (b,h). SA[c] := state ENTERING chunk c.
// SA chunk layout is [n][p]; init_state is [p][n] -> gather on init only.
// ---------------------------------------------------------------------------
__global__ __launch_bounds__(256) void combine_kernel(
    const float* __restrict__ init_state, const float* __restrict__ dtot,
    float* __restrict__ SA)
{
    const int h = blockIdx.x, b = blockIdx.y, tid = threadIdx.x;
    const size_t hd = (size_t)(b * NHEADS + h);
    const int n     = tid >> 1;                 // state index
    const int pbase = (tid & 1) * 32;           // half of the p-row

    float run[32];
    #pragma unroll
    for (int j = 0; j < 32; j++)
        run[j] = init_state[hd * (HEADDIM * DSTATE) + (size_t)(pbase + j) * DSTATE + n];

    for (int c = 0; c < NCHUNK; c++) {
        const float d = dtot[hd * NCHUNK + c];
        float* ps = SA + (hd * NCHUNK + c) * (HEADDIM * DSTATE) + (size_t)n * HEADDIM + pbase;
        #pragma unroll
        for (int j = 0; j < 32; j++) {
            const float loc = ps[j];
            ps[j] = run[j];                     // state entering chunk c
            run[j] = d * run[j] + loc;
        }
    }
}

// ---------------------------------------------------------------------------
// Phase C: per-chunk full scan from true incoming state, with outputs.
// Same layout as phase A; y accumulated fully in-lane (no shuffles),
// every lane stores one coalesced output float per step.
// ---------------------------------------------------------------------------
__global__ __launch_bounds__(256, 1) void out_kernel(
    const float* __restrict__ zx, const float* __restrict__ cw,
    const float* __restrict__ cb,
    const float* __restrict__ Bc, const float* __restrict__ Cc,
    const float2* __restrict__ dtA,
    const float* __restrict__ d_param, const float* __restrict__ SA,
    float* __restrict__ out)
{
    const int c    = blockIdx.x;
    const int h    = blockIdx.y * 4 + (threadIdx.x >> 6);
    const int b    = blockIdx.z;
    const int lane = threadIdx.x & 63;
    const int p    = lane;
    const int t0   = c * Q;
    const int cx   = h * HEADDIM + p;

    const float w0 = cw[(size_t)cx * DCONV + 0];
    const float w1 = cw[(size_t)cx * DCONV + 1];
    const float w2 = cw[(size_t)cx * DCONV + 2];
    const float w3 = cw[(size_t)cx * DCONV + 3];
    const float bx = cb[cx];
    const float Dh = d_param[h];

    const float*  px  = zx + ((size_t)b * LLEN + t0) * DPROJ + DINNER + cx;
    const float*  pz  = zx + ((size_t)b * LLEN + t0) * DPROJ + cx;
    const float4* pB4 = (const float4*)(Bc + ((size_t)b * LLEN + t0) * DSTATE);
    const float4* pC4 = (const float4*)(Cc + ((size_t)b * LLEN + t0) * DSTATE);
    const float2* pd  = dtA + ((size_t)b * LLEN + t0) * NHEADS + h;
    float*        po  = out + ((size_t)b * LLEN + t0) * DINNER + cx;

    float xh0 = 0.f, xh1 = 0.f, xh2 = 0.f;
    if (c > 0) { xh0 = px[-3 * DPROJ]; xh1 = px[-2 * DPROJ]; xh2 = px[-1 * DPROJ]; }

    float st[DSTATE];
    {
        const float* sa = SA + (((size_t)(b * NHEADS + h)) * NCHUNK + c) * (HEADDIM * DSTATE);
        #pragma unroll
        for (int n = 0; n < DSTATE; n++) st[n] = sa[(size_t)n * HEADDIM + p];
    }

    float  xr[2], zr[2]; float2 dr[2];
    xr[0] = px[0];  xr[1] = px[DPROJ];
    zr[0] = pz[0];  zr[1] = pz[DPROJ];
    dr[0] = pd[0];  dr[1] = pd[NHEADS];

    for (int t = 0; t < Q; t++) {
        const float  xraw = xr[t & 1];
        const float  zraw = zr[t & 1];
        const float2 da   = dr[t & 1];
        int tn = t + 2; if (tn > Q - 1) tn = Q - 1;
        xr[t & 1] = px[(size_t)tn * DPROJ];
        zr[t & 1] = pz[(size_t)tn * DPROJ];
        dr[t & 1] = pd[(size_t)tn * NHEADS];

        const float cv   = bx + w0 * xh0 + w1 * xh1 + w2 * xh2 + w3 * xraw;
        const float xs   = cv * sigm(cv);
        const float coef = da.x * xs;
        const float dAv  = da.y;
        xh0 = xh1; xh1 = xh2; xh2 = xraw;

        const float4* rowB = pB4 + (size_t)t * (DSTATE / 4);
        const float4* rowC = pC4 + (size_t)t * (DSTATE / 4);
        float y0 = 0.f, y1 = 0.f, y2 = 0.f, y3 = 0.f;
        #pragma unroll
        for (int half = 0; half < 2; half++) {
            float4 Bt[16], Ct[16];
            #pragma unroll
            for (int i = 0; i < 16; i++) { Bt[i] = rowB[half * 16 + i]; Ct[i] = rowC[half * 16 + i]; }
            #pragma unroll
            for (int i = 0; i < 16; i++) {
                const int n = half * 64 + i * 4;
                st[n + 0] = dAv * st[n + 0] + coef * Bt[i].x;  y0 += st[n + 0] * Ct[i].x;
                st[n + 1] = dAv * st[n + 1] + coef * Bt[i].y;  y1 += st[n + 1] * Ct[i].y;
                st[n + 2] = dAv * st[n + 2] + coef * Bt[i].z;  y2 += st[n + 2] * Ct[i].z;
                st[n + 3] = dAv * st[n + 3] + coef * Bt[i].w;  y3 += st[n + 3] * Ct[i].w;
            }
        }
        const float y  = (y0 + y1) + (y2 + y3) + Dh * xs;
        const float zg = zraw * sigm(zraw);
        po[(size_t)t * DINNER] = y * zg;
    }
}

// ---------------------------------------------------------------------------
extern "C" void kernel_launch(void* const* d_in, const int* in_sizes, int n_in,
                              void* d_out, int out_size, void* d_ws, size_t ws_size,
                              hipStream_t stream) {
    const float* zxbcdt   = (const float*)d_in[0];
    const float* conv_w   = (const float*)d_in[1];
    const float* conv_b   = (const float*)d_in[2];
    const float* dt_bias  = (const float*)d_in[3];
    const float* a_log    = (const float*)d_in[4];
    const float* d_param  = (const float*)d_in[5];
    const float* dt_scale = (const float*)d_in[6];
    const float* init_st  = (const float*)d_in[7];
    const int* dt_min_p   = (const int*)d_in[11];
    const int* dt_max_p   = (const int*)d_in[12];
    float* out = (float*)d_out;

    // workspace: 2 + 2 + 1 + 33.6 + ~0 MB  ~= 38.6 MiB
    char* ws = (char*)d_ws;
    const size_t n_bl = (size_t)BSZ * LLEN;                          // 4096
    float*  Bc  = (float*)ws;  ws += n_bl * DSTATE * sizeof(float);  // 2 MiB
    float*  Cc  = (float*)ws;  ws += n_bl * DSTATE * sizeof(float);  // 2 MiB
    float2* dtA = (float2*)ws; ws += n_bl * NHEADS * sizeof(float2); // 1 MiB
    float*  SA  = (float*)ws;                                        // 33.6 MiB
    ws += (size_t)BSZ * NHEADS * NCHUNK * HEADDIM * DSTATE * sizeof(float);
    float*  dtot = (float*)ws; ws += (size_t)BSZ * NHEADS * NCHUNK * sizeof(float);

    pre_kernel<<<dim3((unsigned)n_bl), 256, 0, stream>>>(
        zxbcdt, conv_w, conv_b, dt_bias, a_log, dt_scale,
        dt_min_p, dt_max_p, Bc, Cc, dtA);

    state_kernel<<<dim3(NCHUNK, NHEADS / 4, BSZ), 256, 0, stream>>>(
        zxbcdt, conv_w, conv_b, Bc, dtA, SA, dtot);

    combine_kernel<<<dim3(NHEADS, BSZ), 256, 0, stream>>>(
        init_st, dtot, SA);

    out_kernel<<<dim3(NCHUNK, NHEADS / 4, BSZ), 256, 0, stream>>>(
        zxbcdt, conv_w, conv_b, Bc, Cc, dtA, d_param, SA, out);
}

// Round 7
// 810.883 us; speedup vs baseline: 1.0057x; 1.0057x over previous
//
#include <hip/hip_runtime.h>
#include <hip/hip_bf16.h>

#define BSZ 2
#define LLEN 2048
#define NHEADS 32
#define HEADDIM 64
#define DSTATE 128
#define DCONV 4
#define DINNER (NHEADS * HEADDIM)                  // 2048
#define DPROJ  (2 * DINNER + 2 * DSTATE + NHEADS)  // 4384
#define Q 128                                      // scan chunk length
#define NCHUNK (LLEN / Q)                          // 16
#define TB 8                                       // y-exchange batch (steps)

__device__ __forceinline__ float sigm(float x) { return 1.0f / (1.0f + __expf(-x)); }

// Robust python-int scalar read (int32 bits or float32 bits).
__device__ __forceinline__ float int_scalar(const int* p) {
    int i = *p;
    if (i >= 0 && i <= 1000000) return (float)i;
    return __int_as_float(i);
}

// ---------------------------------------------------------------------------
// Kernel 1: B/C conv channels + (dt, dA) into fp32 workspace. (proven r5/r6)
// ---------------------------------------------------------------------------
__global__ __launch_bounds__(256) void pre_kernel(
    const float* __restrict__ zx, const float* __restrict__ cw,
    const float* __restrict__ cb, const float* __restrict__ dtb,
    const float* __restrict__ alog, const float* __restrict__ dts,
    const int* __restrict__ mn_p, const int* __restrict__ mx_p,
    float* __restrict__ Bc, float* __restrict__ Cc,
    float2* __restrict__ dtA)
{
    const int bl  = blockIdx.x;            // 0 .. B*L-1
    const int b   = bl / LLEN;
    const int l   = bl % LLEN;
    const int tid = threadIdx.x;           // 0..255 == 2*DSTATE channels

    {
        const int c = DINNER + tid;        // conv channel (B/C region)
        float acc = cb[c];
        #pragma unroll
        for (int k = 0; k < DCONV; k++) {
            int lk = l - (DCONV - 1) + k;
            if (lk >= 0) {
                acc += cw[(size_t)c * DCONV + k] *
                       zx[((size_t)b * LLEN + lk) * DPROJ + DINNER + c];
            }
        }
        float v = acc * sigm(acc);
        if (tid < DSTATE) Bc[(size_t)bl * DSTATE + tid] = v;
        else              Cc[(size_t)bl * DSTATE + (tid - DSTATE)] = v;
    }

    if (tid < NHEADS) {
        float raw = zx[(size_t)bl * DPROJ + (DPROJ - NHEADS) + tid];
        float v   = raw * dts[tid] + dtb[tid];
        float sp  = (v > 20.0f) ? v : log1pf(__expf(v));
        float dt  = fminf(fmaxf(sp, int_scalar(mn_p)), int_scalar(mx_p));
        float A   = -__expf(alog[tid]);
        dtA[(size_t)bl * NHEADS + tid] = make_float2(dt, __expf(dt * A));
    }
}

// ---------------------------------------------------------------------------
// Phase A: per-chunk local end-state (zero init) + total decay.
// WG = 4 waves = 2 heads x 2 n-halves. lane = p; lane holds 64 states
// (float4 st4[16], constant-indexed everywhere -> stays in VGPRs).
// SA layout per (b,h,c): [n][p].
// ---------------------------------------------------------------------------
__global__ __launch_bounds__(256, 2) void state_kernel(
    const float* __restrict__ zx, const float* __restrict__ cw,
    const float* __restrict__ cb,
    const float* __restrict__ Bc, const float2* __restrict__ dtA,
    float* __restrict__ SA, float* __restrict__ dtot)
{
    const int c    = blockIdx.x;                        // chunk
    const int wave = threadIdx.x >> 6;
    const int lane = threadIdx.x & 63;
    const int h    = blockIdx.y * 2 + (wave >> 1);
    const int nh   = wave & 1;                          // n-half
    const int b    = blockIdx.z;
    const int p    = lane;
    const int t0   = c * Q;
    const int cx   = h * HEADDIM + p;
    const int n0   = nh * 64;

    const float w0 = cw[(size_t)cx * DCONV + 0];
    const float w1 = cw[(size_t)cx * DCONV + 1];
    const float w2 = cw[(size_t)cx * DCONV + 2];
    const float w3 = cw[(size_t)cx * DCONV + 3];
    const float bx = cb[cx];

    const float*  px  = zx + ((size_t)b * LLEN + t0) * DPROJ + DINNER + cx;
    const float4* pB4 = (const float4*)(Bc + ((size_t)b * LLEN + t0) * DSTATE + n0);
    const float2* pd  = dtA + ((size_t)b * LLEN + t0) * NHEADS + h;

    float xh0 = 0.f, xh1 = 0.f, xh2 = 0.f;              // conv history
    if (c > 0) { xh0 = px[-3 * DPROJ]; xh1 = px[-2 * DPROJ]; xh2 = px[-1 * DPROJ]; }

    float4 st4[16];
    #pragma unroll
    for (int i = 0; i < 16; i++) st4[i] = make_float4(0.f, 0.f, 0.f, 0.f);
    float aprod = 1.f;

    // depth-2 ring, constant-indexed via unrolled u
    float xr[2]; float2 dr[2];
    xr[0] = px[0];  xr[1] = px[DPROJ];
    dr[0] = pd[0];  dr[1] = pd[NHEADS];

    for (int tb = 0; tb < Q; tb += 2) {
        #pragma unroll
        for (int u = 0; u < 2; u++) {
            const int t = tb + u;
            const float  xraw = xr[u];
            const float2 da   = dr[u];
            int tn = t + 2; if (tn > Q - 1) tn = Q - 1;
            xr[u] = px[(size_t)tn * DPROJ];
            dr[u] = pd[(size_t)tn * NHEADS];

            const float cv   = bx + w0 * xh0 + w1 * xh1 + w2 * xh2 + w3 * xraw;
            const float xs   = cv * sigm(cv);
            const float coef = da.x * xs;
            const float dAv  = da.y;
            aprod *= dAv;
            xh0 = xh1; xh1 = xh2; xh2 = xraw;

            const float4* rB = pB4 + (size_t)t * (DSTATE / 4);
            #pragma unroll
            for (int i = 0; i < 16; i++) {
                const float4 Bv = rB[i];
                float4 s = st4[i];
                s.x = dAv * s.x + coef * Bv.x;
                s.y = dAv * s.y + coef * Bv.y;
                s.z = dAv * s.z + coef * Bv.z;
                s.w = dAv * s.w + coef * Bv.w;
                st4[i] = s;
            }
        }
    }

    float* sa = SA + (((size_t)(b * NHEADS + h)) * NCHUNK + c) * (HEADDIM * DSTATE);
    #pragma unroll
    for (int i = 0; i < 16; i++) {
        const int n = n0 + 4 * i;
        sa[(size_t)(n + 0) * HEADDIM + p] = st4[i].x;
        sa[(size_t)(n + 1) * HEADDIM + p] = st4[i].y;
        sa[(size_t)(n + 2) * HEADDIM + p] = st4[i].z;
        sa[(size_t)(n + 3) * HEADDIM + p] = st4[i].w;
    }
    if (lane == 0 && nh == 0)
        dtot[((size_t)(b * NHEADS + h)) * NCHUNK + c] = aprod;
}

// ---------------------------------------------------------------------------
// Phase B: sequential chunk combine per (b,h). SA[c] := state ENTERING chunk c.
// (proven correct in round 6)
// ---------------------------------------------------------------------------
__global__ __launch_bounds__(256) void combine_kernel(
    const float* __restrict__ init_state, const float* __restrict__ dtot,
    float* __restrict__ SA)
{
    const int h = blockIdx.x, b = blockIdx.y, tid = threadIdx.x;
    const size_t hd = (size_t)(b * NHEADS + h);
    const int n     = tid >> 1;                 // state index
    const int pbase = (tid & 1) * 32;           // half of the p-row

    float run[32];
    #pragma unroll
    for (int j = 0; j < 32; j++)
        run[j] = init_state[hd * (HEADDIM * DSTATE) + (size_t)(pbase + j) * DSTATE + n];

    for (int c = 0; c < NCHUNK; c++) {
        const float d = dtot[hd * NCHUNK + c];
        float* ps = SA + (hd * NCHUNK + c) * (HEADDIM * DSTATE) + (size_t)n * HEADDIM + pbase;
        #pragma unroll
        for (int j = 0; j < 32; j++) {
            const float loc = ps[j];
            ps[j] = run[j];                     // state entering chunk c
            run[j] = d * run[j] + loc;
        }
    }
}

// ---------------------------------------------------------------------------
// Phase C: per-chunk full scan from true incoming state, with outputs.
// Same layout as phase A. Partial y (64 n's) per wave; 8-step batches are
// exchanged across the two n-half waves via 4 KB LDS (2 barriers / 8 steps).
// ---------------------------------------------------------------------------
__global__ __launch_bounds__(256, 2) void out_kernel(
    const float* __restrict__ zx, const float* __restrict__ cw,
    const float* __restrict__ cb,
    const float* __restrict__ Bc, const float* __restrict__ Cc,
    const float2* __restrict__ dtA,
    const float* __restrict__ d_param, const float* __restrict__ SA,
    float* __restrict__ out)
{
    const int c    = blockIdx.x;
    const int wave = threadIdx.x >> 6;
    const int lane = threadIdx.x & 63;
    const int h    = blockIdx.y * 2 + (wave >> 1);
    const int hl   = wave >> 1;                         // head slot in WG
    const int nh   = wave & 1;                          // n-half
    const int b    = blockIdx.z;
    const int p    = lane;
    const int t0   = c * Q;
    const int cx   = h * HEADDIM + p;
    const int n0   = nh * 64;

    __shared__ float xch[2][TB][64];                    // 4 KB

    const float w0 = cw[(size_t)cx * DCONV + 0];
    const float w1 = cw[(size_t)cx * DCONV + 1];
    const float w2 = cw[(size_t)cx * DCONV + 2];
    const float w3 = cw[(size_t)cx * DCONV + 3];
    const float bx = cb[cx];
    const float Dh = d_param[h];

    const float*  px  = zx + ((size_t)b * LLEN + t0) * DPROJ + DINNER + cx;
    const float*  pz  = zx + ((size_t)b * LLEN + t0) * DPROJ + cx;
    const float4* pB4 = (const float4*)(Bc + ((size_t)b * LLEN + t0) * DSTATE + n0);
    const float4* pC4 = (const float4*)(Cc + ((size_t)b * LLEN + t0) * DSTATE + n0);
    const float2* pd  = dtA + ((size_t)b * LLEN + t0) * NHEADS + h;
    float*        po  = out + ((size_t)b * LLEN + t0) * DINNER + cx;

    float xh0 = 0.f, xh1 = 0.f, xh2 = 0.f;
    if (c > 0) { xh0 = px[-3 * DPROJ]; xh1 = px[-2 * DPROJ]; xh2 = px[-1 * DPROJ]; }

    float4 st4[16];
    {
        const float* sa = SA + (((size_t)(b * NHEADS + h)) * NCHUNK + c) * (HEADDIM * DSTATE);
        #pragma unroll
        for (int i = 0; i < 16; i++) {
            const int n = n0 + 4 * i;
            st4[i].x = sa[(size_t)(n + 0) * HEADDIM + p];
            st4[i].y = sa[(size_t)(n + 1) * HEADDIM + p];
            st4[i].z = sa[(size_t)(n + 2) * HEADDIM + p];
            st4[i].w = sa[(size_t)(n + 3) * HEADDIM + p];
        }
    }

    float xr[2], zr[2]; float2 dr[2];
    xr[0] = px[0];  xr[1] = px[DPROJ];
    zr[0] = pz[0];  zr[1] = pz[DPROJ];
    dr[0] = pd[0];  dr[1] = pd[NHEADS];

    for (int tb = 0; tb < Q; tb += TB) {
        float yp[TB], xsv[TB], zgv[TB];
        #pragma unroll
        for (int j = 0; j < TB; j++) {
            const int t = tb + j;
            const float  xraw = xr[j & 1];
            const float  zraw = zr[j & 1];
            const float2 da   = dr[j & 1];
            int tn = t + 2; if (tn > Q - 1) tn = Q - 1;
            xr[j & 1] = px[(size_t)tn * DPROJ];
            zr[j & 1] = pz[(size_t)tn * DPROJ];
            dr[j & 1] = pd[(size_t)tn * NHEADS];

            const float cv   = bx + w0 * xh0 + w1 * xh1 + w2 * xh2 + w3 * xraw;
            const float xs   = cv * sigm(cv);
            const float coef = da.x * xs;
            const float dAv  = da.y;
            xh0 = xh1; xh1 = xh2; xh2 = xraw;

            const float4* rB = pB4 + (size_t)t * (DSTATE / 4);
            const float4* rC = pC4 + (size_t)t * (DSTATE / 4);
            float acc = 0.f;
            #pragma unroll
            for (int i = 0; i < 16; i++) {
                const float4 Bv = rB[i];
                const float4 Cv = rC[i];
                float4 s = st4[i];
                s.x = dAv * s.x + coef * Bv.x;  acc += s.x * Cv.x;
                s.y = dAv * s.y + coef * Bv.y;  acc += s.y * Cv.y;
                s.z = dAv * s.z + coef * Bv.z;  acc += s.z * Cv.z;
                s.w = dAv * s.w + coef * Bv.w;  acc += s.w * Cv.w;
                st4[i] = s;
            }
            yp[j]  = acc;
            xsv[j] = xs;
            zgv[j] = zraw * sigm(zraw);
        }

        __syncthreads();                      // prior batch's reads complete
        if (nh == 1) {
            #pragma unroll
            for (int j = 0; j < TB; j++) xch[hl][j][lane] = yp[j];
        }
        __syncthreads();                      // partials visible
        if (nh == 0) {
            #pragma unroll
            for (int j = 0; j < TB; j++) {
                const float y = yp[j] + xch[hl][j][lane] + Dh * xsv[j];
                po[(size_t)(tb + j) * DINNER] = y * zgv[j];
            }
        }
    }
}

// ---------------------------------------------------------------------------
extern "C" void kernel_launch(void* const* d_in, const int* in_sizes, int n_in,
                              void* d_out, int out_size, void* d_ws, size_t ws_size,
                              hipStream_t stream) {
    const float* zxbcdt   = (const float*)d_in[0];
    const float* conv_w   = (const float*)d_in[1];
    const float* conv_b   = (const float*)d_in[2];
    const float* dt_bias  = (const float*)d_in[3];
    const float* a_log    = (const float*)d_in[4];
    const float* d_param  = (const float*)d_in[5];
    const float* dt_scale = (const float*)d_in[6];
    const float* init_st  = (const float*)d_in[7];
    const int* dt_min_p   = (const int*)d_in[11];
    const int* dt_max_p   = (const int*)d_in[12];
    float* out = (float*)d_out;

    // workspace: 2 + 2 + 1 + 33.6 MB + ~0  ~= 38.6 MiB
    char* ws = (char*)d_ws;
    const size_t n_bl = (size_t)BSZ * LLEN;                          // 4096
    float*  Bc  = (float*)ws;  ws += n_bl * DSTATE * sizeof(float);  // 2 MiB
    float*  Cc  = (float*)ws;  ws += n_bl * DSTATE * sizeof(float);  // 2 MiB
    float2* dtA = (float2*)ws; ws += n_bl * NHEADS * sizeof(float2); // 1 MiB
    float*  SA  = (float*)ws;                                        // 33.6 MiB
    ws += (size_t)BSZ * NHEADS * NCHUNK * HEADDIM * DSTATE * sizeof(float);
    float*  dtot = (float*)ws; ws += (size_t)BSZ * NHEADS * NCHUNK * sizeof(float);

    pre_kernel<<<dim3((unsigned)n_bl), 256, 0, stream>>>(
        zxbcdt, conv_w, conv_b, dt_bias, a_log, dt_scale,
        dt_min_p, dt_max_p, Bc, Cc, dtA);

    state_kernel<<<dim3(NCHUNK, NHEADS / 2, BSZ), 256, 0, stream>>>(
        zxbcdt, conv_w, conv_b, Bc, dtA, SA, dtot);

    combine_kernel<<<dim3(NHEADS, BSZ), 256, 0, stream>>>(
        init_st, dtot, SA);

    out_kernel<<<dim3(NCHUNK, NHEADS / 2, BSZ), 256, 0, stream>>>(
        zxbcdt, conv_w, conv_b, Bc, Cc, dtA, d_param, SA, out);
}